// Round 2
// baseline (261.231 us; speedup 1.0000x reference)
//
#include <hip/hip_runtime.h>

typedef __bf16 v8bf __attribute__((ext_vector_type(8)));
typedef float  v4f  __attribute__((ext_vector_type(4)));
typedef unsigned short u16;

__device__ __forceinline__ u16 f2bf(float f){
  union { float f; unsigned int i; } v; v.f = f;
  return (u16)((v.i + 0x7fffu + ((v.i >> 16) & 1u)) >> 16);
}
__device__ __forceinline__ v4f v4zero(){ v4f z; z[0]=0.f; z[1]=0.f; z[2]=0.f; z[3]=0.f; return z; }

#define MFMA16(a,b,c) __builtin_amdgcn_mfma_f32_16x16x32_bf16((a),(b),(c),0,0,0)

// ============ f32 -> bf16 bulk convert (n multiple of 1024) ============
__global__ __launch_bounds__(256) void cvt_kernel(const float* __restrict__ src, u16* __restrict__ dst, int n){
  int i = (blockIdx.x*256 + threadIdx.x)*4;
  if (i < n){
    float4 v = *(const float4*)(src + i);
    ushort4 o;
    o.x = f2bf(v.x); o.y = f2bf(v.y); o.z = f2bf(v.z); o.w = f2bf(v.w);
    *(ushort4*)(dst + i) = o;
  }
}

// ============ GroupNorm stats: one block per (b,g); 16ch x 1024 f32 contiguous ============
__global__ __launch_bounds__(256) void gn_stats_kernel(const float* __restrict__ x, float* __restrict__ stats){
  const float* base = x + (size_t)blockIdx.x * 16384;
  float s = 0.f, ss = 0.f;
  #pragma unroll
  for (int it = 0; it < 16; ++it){
    float4 v = *(const float4*)(base + it*1024 + threadIdx.x*4);
    s  += v.x + v.y + v.z + v.w;
    ss += v.x*v.x + v.y*v.y + v.z*v.z + v.w*v.w;
  }
  #pragma unroll
  for (int off = 32; off > 0; off >>= 1){ s += __shfl_down(s, off); ss += __shfl_down(ss, off); }
  __shared__ float red[8];
  int w = threadIdx.x >> 6;
  if ((threadIdx.x & 63) == 0){ red[w] = s; red[4+w] = ss; }
  __syncthreads();
  if (threadIdx.x == 0){
    float S  = red[0]+red[1]+red[2]+red[3];
    float SS = red[4]+red[5]+red[6]+red[7];
    float mean = S * (1.f/16384.f);
    float var  = SS * (1.f/16384.f) - mean*mean;
    stats[blockIdx.x*2]   = mean;
    stats[blockIdx.x*2+1] = rsqrtf(var + 1e-5f);
  }
}

// ============ GroupNorm apply + transpose: f32 x -> bf16 h_t[b][n][c] ============
__global__ __launch_bounds__(256) void gn_apply_kernel(const float* __restrict__ x, const float* __restrict__ nw,
                                                       const float* __restrict__ nb, const float* __restrict__ stats,
                                                       u16* __restrict__ h_t){
  __shared__ u16 tile[32*520];   // [n_local 32][c 512 + pad 8]
  int b = blockIdx.y, n0 = blockIdx.x*32, tid = threadIdx.x;
  int cr = tid >> 2, nn = (tid & 3)*8;
  #pragma unroll
  for (int p = 0; p < 8; ++p){
    int c = p*64 + cr;
    const float* px = x + (size_t)(b*512 + c)*1024 + n0 + nn;
    float4 u0 = *(const float4*)(px);
    float4 u1 = *(const float4*)(px + 4);
    int g = c >> 4;
    float mean = stats[(b*32+g)*2], rstd = stats[(b*32+g)*2+1];
    float wv = nw[c], bv = nb[c];
    float vals[8] = {u0.x,u0.y,u0.z,u0.w,u1.x,u1.y,u1.z,u1.w};
    #pragma unroll
    for (int e = 0; e < 8; ++e)
      tile[(nn+e)*520 + c] = f2bf((vals[e] - mean)*rstd*wv + bv);
  }
  __syncthreads();
  #pragma unroll
  for (int p = 0; p < 8; ++p){
    int n  = p*4 + (tid >> 6);
    int c0 = (tid & 63)*8;
    *(int4*)(h_t + ((size_t)b*1024 + n0 + n)*512 + c0) = *(int4*)(tile + n*520 + c0);
  }
}

// ============ Generic bf16 GEMM: C[M][N] = A[M][K] * B[N][K]^T ============
// bf16 output via Cbf, or f32 output via Cf (+ optional f32 residual).
// grid (N/128, M/128, batch), 256 threads (4 waves, each 64x64).
__global__ __launch_bounds__(256,2) void gemm_bt_kernel(
    const u16* __restrict__ A, long long sA,
    const u16* __restrict__ B, long long sB,
    u16* __restrict__ Cbf, float* __restrict__ Cf, long long sC,
    const float* __restrict__ bias_row,
    const float* __restrict__ bias_col,
    const float* __restrict__ residf, long long sR,
    int M, int N, int K)
{
  __shared__ u16 smem[18432];             // staging: As[128][40] + Bs[128][40]; epilogue: 4x [64][72]
  u16* As = smem;
  u16* Bs = smem + 128*40;
  const int tid = threadIdx.x, w = tid>>6, lane = tid&63, col = lane&15, quad = lane>>4;
  const int m0 = blockIdx.y*128, n0 = blockIdx.x*128;
  const u16* Ab = A + (size_t)blockIdx.z*sA;
  const u16* Bb = B + (size_t)blockIdx.z*sB;
  const int sr = tid>>2, sk = (tid&3)*8;
  const int mw = (w&1)*64, nw = (w>>1)*64;

  v4f acc[4][4];
  #pragma unroll
  for (int i=0;i<4;++i)
    #pragma unroll
    for (int j=0;j<4;++j) acc[i][j] = v4zero();

  for (int kt = 0; kt < K; kt += 32){
    *(int4*)(As + sr*40 + sk)      = *(const int4*)(Ab + (size_t)(m0+sr)*K    + kt + sk);
    *(int4*)(As + (64+sr)*40 + sk) = *(const int4*)(Ab + (size_t)(m0+64+sr)*K + kt + sk);
    *(int4*)(Bs + sr*40 + sk)      = *(const int4*)(Bb + (size_t)(n0+sr)*K    + kt + sk);
    *(int4*)(Bs + (64+sr)*40 + sk) = *(const int4*)(Bb + (size_t)(n0+64+sr)*K + kt + sk);
    __syncthreads();
    v8bf a[4], bb[4];
    #pragma unroll
    for (int i = 0; i < 4; ++i) a[i]  = *(const v8bf*)(As + (mw+i*16+col)*40 + quad*8);
    #pragma unroll
    for (int j = 0; j < 4; ++j) bb[j] = *(const v8bf*)(Bs + (nw+j*16+col)*40 + quad*8);
    #pragma unroll
    for (int i = 0; i < 4; ++i)
      #pragma unroll
      for (int j = 0; j < 4; ++j)
        acc[i][j] = MFMA16(a[i], bb[j], acc[i][j]);
    __syncthreads();
  }

  float br[4][4], bc[4];
  #pragma unroll
  for (int i = 0; i < 4; ++i)
    #pragma unroll
    for (int r = 0; r < 4; ++r)
      br[i][r] = bias_row ? bias_row[m0+mw+i*16+quad*4+r] : 0.f;
  #pragma unroll
  for (int j = 0; j < 4; ++j)
    bc[j] = bias_col ? bias_col[n0+nw+j*16+col] : 0.f;

  if (Cf){
    // f32 direct store (+ optional f32 residual), 64B-segment coalescing
    float* Cb = Cf + (size_t)blockIdx.z*sC;
    const float* Rb = residf ? residf + (size_t)blockIdx.z*sR : nullptr;
    #pragma unroll
    for (int i = 0; i < 4; ++i)
      #pragma unroll
      for (int r = 0; r < 4; ++r){
        int row = m0+mw+i*16+quad*4+r;
        #pragma unroll
        for (int j = 0; j < 4; ++j){
          size_t goff = (size_t)row*N + n0+nw+j*16+col;
          float val = acc[i][j][r] + br[i][r] + bc[j];
          if (Rb) val += Rb[goff];
          Cb[goff] = val;
        }
      }
  } else {
    // bf16 store via LDS bounce for 16B coalesced writes
    u16* Cs = smem + w*(64*72);             // per-wave [64][64+8]
    #pragma unroll
    for (int i = 0; i < 4; ++i)
      #pragma unroll
      for (int j = 0; j < 4; ++j)
        #pragma unroll
        for (int r = 0; r < 4; ++r)
          Cs[(i*16+quad*4+r)*72 + j*16+col] = f2bf(acc[i][j][r] + br[i][r] + bc[j]);
    __syncthreads();
    u16* Cb = Cbf + (size_t)blockIdx.z*sC;
    #pragma unroll
    for (int p = 0; p < 8; ++p){
      int rl = p*8 + (lane>>3), cl = (lane&7)*8;
      size_t goff = (size_t)(m0+mw+rl)*N + n0+nw+cl;
      *(int4*)(Cb + goff) = *(int4*)(Cs + rl*72 + cl);
    }
  }
}

// ============ Fused flash attention (bf16 ws in/out, fp32 softmax) ============
// qk[b][n][0..511]=q, qk[b][n][512..1023]=k; vv[b][c_all][m]; out[b][n][c_all]
// grid (8 q-tiles, 4 heads, 16 batch); 256 threads; wave w owns q rows [w*32, w*32+32).
__global__ __launch_bounds__(256,2) void attn_kernel(const u16* __restrict__ qk, const u16* __restrict__ vv,
                                                     u16* __restrict__ outp){
  __shared__ u16 smem[27136];
  u16* Ks = smem;                    // [m 64][c 128+8]
  u16* Vs = smem + 64*136;           // [c 128][m 64+8]
  u16* Ps = smem + 64*136 + 128*72;  // [n 128][m 64+8]
  const int b = blockIdx.z, h = blockIdx.y, n0 = blockIdx.x*128;
  const int tid = threadIdx.x, w = tid>>6, lane = tid&63, col = lane&15, quad = lane>>4;
  const size_t bq = (size_t)b*1024*1024;
  const float scale = 0.08838834764831845f;  // 1/sqrt(128)

  v8bf aq[2][4];
  #pragma unroll
  for (int i = 0; i < 2; ++i)
    #pragma unroll
    for (int kk = 0; kk < 4; ++kk)
      aq[i][kk] = *(const v8bf*)(qk + bq + (size_t)(n0 + w*32 + i*16 + col)*1024 + h*128 + kk*32 + quad*8);

  v4f o[2][8];
  #pragma unroll
  for (int i=0;i<2;++i)
    #pragma unroll
    for (int j=0;j<8;++j) o[i][j] = v4zero();
  float mi[8], li[8];
  #pragma unroll
  for (int r=0;r<8;++r){ mi[r] = -1e30f; li[r] = 0.f; }

  const int ksr = tid>>4, ksc = (tid&15)*8;
  const int vsr = tid>>3, vsc = (tid&7)*8;

  for (int mt = 0; mt < 1024; mt += 64){
    #pragma unroll
    for (int p = 0; p < 4; ++p)
      *(int4*)(Ks + (p*16 + ksr)*136 + ksc) =
        *(const int4*)(qk + bq + (size_t)(mt + p*16 + ksr)*1024 + 512 + h*128 + ksc);
    #pragma unroll
    for (int p = 0; p < 4; ++p)
      *(int4*)(Vs + (p*32 + vsr)*72 + vsc) =
        *(const int4*)(vv + ((size_t)b*512 + h*128 + p*32 + vsr)*1024 + mt + vsc);
    __syncthreads();

    // S = Q K^T
    v4f s[2][4];
    #pragma unroll
    for (int i=0;i<2;++i)
      #pragma unroll
      for (int j=0;j<4;++j) s[i][j] = v4zero();
    #pragma unroll
    for (int kk = 0; kk < 4; ++kk){
      v8bf bk[4];
      #pragma unroll
      for (int j = 0; j < 4; ++j) bk[j] = *(const v8bf*)(Ks + (j*16+col)*136 + kk*32 + quad*8);
      #pragma unroll
      for (int i = 0; i < 2; ++i)
        #pragma unroll
        for (int j = 0; j < 4; ++j)
          s[i][j] = MFMA16(aq[i][kk], bk[j], s[i][j]);
    }
    #pragma unroll
    for (int i=0;i<2;++i)
      #pragma unroll
      for (int j=0;j<4;++j) s[i][j] = s[i][j] * scale;

    // online softmax per row (row = i*16 + quad*4 + r; this lane's cols: j*16+col)
    #pragma unroll
    for (int i = 0; i < 2; ++i)
      #pragma unroll
      for (int r = 0; r < 4; ++r){
        float mx = -1e30f;
        #pragma unroll
        for (int j = 0; j < 4; ++j) mx = fmaxf(mx, s[i][j][r]);
        mx = fmaxf(mx, __shfl_xor(mx, 1));
        mx = fmaxf(mx, __shfl_xor(mx, 2));
        mx = fmaxf(mx, __shfl_xor(mx, 4));
        mx = fmaxf(mx, __shfl_xor(mx, 8));
        int ir = i*4 + r;
        float mnew  = fmaxf(mi[ir], mx);
        float alpha = __expf(mi[ir] - mnew);
        float rsum = 0.f;
        #pragma unroll
        for (int j = 0; j < 4; ++j){
          float pv = __expf(s[i][j][r] - mnew);
          s[i][j][r] = pv;
          rsum += pv;
        }
        rsum += __shfl_xor(rsum, 1);
        rsum += __shfl_xor(rsum, 2);
        rsum += __shfl_xor(rsum, 4);
        rsum += __shfl_xor(rsum, 8);
        li[ir] = li[ir]*alpha + rsum;
        mi[ir] = mnew;
        #pragma unroll
        for (int j = 0; j < 8; ++j) o[i][j][r] *= alpha;
      }

    // P: C-layout regs -> LDS -> A-operand layout
    #pragma unroll
    for (int i = 0; i < 2; ++i)
      #pragma unroll
      for (int j = 0; j < 4; ++j)
        #pragma unroll
        for (int r = 0; r < 4; ++r)
          Ps[(w*32 + i*16 + quad*4 + r)*72 + j*16 + col] = f2bf(s[i][j][r]);
    __syncthreads();

    // O += P * V^T
    #pragma unroll
    for (int kk = 0; kk < 2; ++kk){
      v8bf ap[2];
      #pragma unroll
      for (int i = 0; i < 2; ++i)
        ap[i] = *(const v8bf*)(Ps + (w*32 + i*16 + col)*72 + kk*32 + quad*8);
      #pragma unroll
      for (int j = 0; j < 8; ++j){
        v8bf bv = *(const v8bf*)(Vs + (j*16+col)*72 + kk*32 + quad*8);
        #pragma unroll
        for (int i = 0; i < 2; ++i) o[i][j] = MFMA16(ap[i], bv, o[i][j]);
      }
    }
    __syncthreads();
  }

  #pragma unroll
  for (int i = 0; i < 2; ++i)
    #pragma unroll
    for (int r = 0; r < 4; ++r){
      float inv = 1.f / li[i*4+r];
      #pragma unroll
      for (int j = 0; j < 8; ++j) o[i][j][r] *= inv;
    }

  // bounce O through LDS for coalesced 16B stores; out layout [b][n][c_all]
  u16* Os = smem;   // [128][136]
  #pragma unroll
  for (int i = 0; i < 2; ++i)
    #pragma unroll
    for (int j = 0; j < 8; ++j)
      #pragma unroll
      for (int r = 0; r < 4; ++r)
        Os[(w*32 + i*16 + quad*4 + r)*136 + j*16 + col] = f2bf(o[i][j][r]);
  __syncthreads();
  #pragma unroll
  for (int p = 0; p < 8; ++p){
    int nr = p*16 + (tid>>4);
    int c8 = (tid&15)*8;
    *(int4*)(outp + ((size_t)b*1024 + n0 + nr)*512 + h*128 + c8) = *(int4*)(Os + nr*136 + c8);
  }
}

extern "C" void kernel_launch(void* const* d_in, const int* in_sizes, int n_in,
                              void* d_out, int out_size, void* d_ws, size_t ws_size,
                              hipStream_t stream){
  const float* x      = (const float*)d_in[0];
  const float* norm_w = (const float*)d_in[1];
  const float* norm_b = (const float*)d_in[2];
  const float* qkv_w  = (const float*)d_in[3];
  const float* qkv_b  = (const float*)d_in[4];
  const float* proj_w = (const float*)d_in[5];
  const float* proj_b = (const float*)d_in[6];
  float* out = (float*)d_out;

  // workspace layout (bf16 elements unless noted): ~69.3 MB total
  u16* h_t   = (u16*)d_ws;                                  // [16][1024][512]  normalized, transposed
  u16* qk_t  = h_t  + (size_t)16*1024*512;                  // [16][1024][1024] q|k, [n][o] layout
  u16* v_ws  = qk_t + (size_t)16*1024*1024;                 // [16][512][1024]  v, [c][n] layout
  u16* wq_bf = v_ws + (size_t)16*512*1024;                  // [1536][512] qkv_w bf16
  u16* wp_bf = wq_bf + (size_t)1536*512;                    // [512][512]  proj_w bf16
  float* stats = (float*)(wp_bf + (size_t)512*512);         // [512][2] mean/rstd
  u16* attnout = h_t;                                       // reuse h_t (consumed before attention)

  cvt_kernel<<<768, 256, 0, stream>>>(qkv_w, wq_bf, 1536*512);
  cvt_kernel<<<256, 256, 0, stream>>>(proj_w, wp_bf, 512*512);
  gn_stats_kernel<<<512, 256, 0, stream>>>(x, stats);
  gn_apply_kernel<<<dim3(32,16), 256, 0, stream>>>(x, norm_w, norm_b, stats, h_t);

  // qk_t[b][n][o] = h_t[b][n][:] . qkv_w[o][:] + qkv_b[o]   (o in [0,1024))
  gemm_bt_kernel<<<dim3(8,8,16), 256, 0, stream>>>(
      h_t, (long long)1024*512, wq_bf, 0,
      qk_t, nullptr, (long long)1024*1024, nullptr, qkv_b, nullptr, 0, 1024, 1024, 512);

  // v_ws[b][o][n] = qkv_w[1024+o][:] . h_t[b][n][:] + qkv_b[1024+o]
  gemm_bt_kernel<<<dim3(8,4,16), 256, 0, stream>>>(
      wq_bf + (size_t)1024*512, 0, h_t, (long long)1024*512,
      v_ws, nullptr, (long long)512*1024, qkv_b + 1024, nullptr, nullptr, 0, 512, 1024, 512);

  attn_kernel<<<dim3(8,4,16), 256, 0, stream>>>(qk_t, v_ws, attnout);

  // out[b][o][n] = proj_w[o][:] . attnout[b][n][:] + proj_b[o] + x[b][o][n]
  gemm_bt_kernel<<<dim3(8,4,16), 256, 0, stream>>>(
      wp_bf, 0, attnout, (long long)1024*512,
      nullptr, out, (long long)512*1024, proj_b, nullptr, x, (long long)512*1024, 512, 1024, 512);
}